// Round 2
// baseline (700.294 us; speedup 1.0000x reference)
//
#include <hip/hip_runtime.h>
#include <hip/hip_fp16.h>

// SeqAttnMatch: B=8, L1=2048, L2=2048, H=1024
//   x_proj = relu(x @ W1^T + b1); y_proj = relu(y @ W2^T + b2)
//   scores = x_proj @ y_proj^T; mask; softmax over L2; out = alpha @ y
// fp16 MFMA GEMMs (f32 accum). Workspace kept under ~172 MB by chunking the
// scores/softmax/PV phase over 2 batches at a time, overlaid on dead buffers.

using half8 = __attribute__((ext_vector_type(8))) _Float16;
using f32x4 = __attribute__((ext_vector_type(4))) float;

#define DEVI __device__ __forceinline__

DEVI void async16(void* lds, const void* g) {
    __builtin_amdgcn_global_load_lds(
        (const __attribute__((address_space(1))) unsigned int*)g,
        (__attribute__((address_space(3))) unsigned int*)lds,
        16, 0, 0);
}

DEVI unsigned short f2h(float f) { return __half_as_ushort(__float2half(f)); }

// ---------------------------------------------------------------- converts
__global__ __launch_bounds__(256) void cvt_f32_f16_kernel(
    const float4* __restrict__ in, ushort4* __restrict__ out, int n4)
{
    int i = blockIdx.x * 256 + threadIdx.x;
    if (i >= n4) return;
    float4 f = in[i];
    ushort4 o;
    o.x = f2h(f.x); o.y = f2h(f.y); o.z = f2h(f.z); o.w = f2h(f.w);
    out[i] = o;
}

// ---------------------------------------------------------------- mask decode
// y_mask is bool[8][2048]. It may arrive as uint8 (1B), int32 (4B) or f32
// (4B). Classify by byte-lane statistics over the first 16384 bytes (valid
// reads for every candidate dtype):
//   4B int: bytes at i%4!=0 all zero              -> mode 1
//   f32 (0.0/1.0): bytes at i%4==0 all zero       -> mode 2
//   uint8: neither                                -> mode 0
__global__ void mask_prep_kernel(const unsigned char* __restrict__ raw,
                                 unsigned char* __restrict__ mask)
{
    __shared__ int S0, S123;
    const int t = threadIdx.x;
    if (t == 0) { S0 = 0; S123 = 0; }
    __syncthreads();
    int s0 = 0, s123 = 0;
    for (int i = t; i < 16384; i += 256) {
        int v = raw[i];
        if ((i & 3) == 0) s0 += v; else s123 += v;
    }
    atomicAdd(&S0, s0); atomicAdd(&S123, s123);
    __syncthreads();
    const int mode = (S123 == 0) ? 1 : ((S0 == 0) ? 2 : 0);
    for (int i = t; i < 16384; i += 256) {
        unsigned char m;
        if (mode == 0)      m = raw[i] ? 1 : 0;
        else if (mode == 1) m = ((const int*)raw)[i] ? 1 : 0;
        else                m = (((const float*)raw)[i] != 0.f) ? 1 : 0;
        mask[i] = m;
    }
}

// ---------------------------------------------------------------- transpose
// yh [B, L2=2048, H=1024] fp16 -> yT [B, H=1024, L2=2048] fp16
__global__ __launch_bounds__(256) void transpose_kernel(
    const unsigned short* __restrict__ y, unsigned short* __restrict__ yT)
{
    const int b  = blockIdx.z;
    const int i0 = blockIdx.x * 64;   // L2 tile
    const int h0 = blockIdx.y * 64;   // H tile
    __shared__ unsigned short tile[64][72];
    const int t  = threadIdx.x;
    const int tr = t >> 4;            // 0..15
    const int tc = (t & 15) * 4;      // 0..60
    const size_t ybase = ((size_t)b * 2048 + i0) * 1024 + h0;
#pragma unroll
    for (int p = 0; p < 4; ++p) {
        const int r = p * 16 + tr;
        ushort4 v = *(const ushort4*)(y + ybase + (size_t)r * 1024 + tc);
        *(ushort4*)&tile[r][tc] = v;
    }
    __syncthreads();
    const size_t obase = ((size_t)b * 1024 + h0) * 2048 + i0;
#pragma unroll
    for (int p = 0; p < 4; ++p) {
        const int r = p * 16 + tr;    // h offset
        ushort4 v;
        v.x = tile[tc + 0][r]; v.y = tile[tc + 1][r];
        v.z = tile[tc + 2][r]; v.w = tile[tc + 3][r];
        *(ushort4*)(yT + obase + (size_t)r * 2048 + tc) = v;
    }
}

// ---------------------------------------------------------------- GEMM (B^T)
// C[m,n] = act( sum_k A[m,k] * Bt[n,k] + bias[n] ), fp16 in, f32 accum.
// m97 structure: 128x128 tile, BK=32, 4 waves (2x2 of 64x64),
// global_load_lds width 16, mfma_f32_16x16x32_f16.
template<typename OutT, bool RELU, bool BIAS>
__global__ __launch_bounds__(256) void gemm_bt_kernel(
    const unsigned short* __restrict__ A,
    const unsigned short* __restrict__ Bt,
    OutT* __restrict__ C,
    const float* __restrict__ bias,
    int K, int N,
    long long sA, long long sB, long long sC)
{
    __shared__ __align__(16) unsigned short As[128 * 32];
    __shared__ __align__(16) unsigned short Bs[128 * 32];

    const int t    = threadIdx.x;
    const int lane = t & 63;
    const int wave = t >> 6;
    const int wr   = wave >> 1;       // 0..1
    const int wc   = wave & 1;        // 0..1
    const int m0   = blockIdx.x * 128;
    const int n0   = blockIdx.y * 128;
    const int b    = blockIdx.z;
    A  += (size_t)b * sA;
    Bt += (size_t)b * sB;
    C  += (size_t)b * sC;

    // staging: thread t covers bytes [t*16, t*16+16) of each 4KB half-tile
    const int off  = t * 16;          // byte offset in LDS chunk
    const int srow = off >> 6;        // 64B per row (32 fp16)
    const int scb  = off & 63;        // byte within row
    const unsigned short* Ag = A + (size_t)(m0 + srow) * K + (scb >> 1);
    const unsigned short* Bg = Bt + (size_t)(n0 + srow) * K + (scb >> 1);
    char* AsD = (char*)As + off;
    char* BsD = (char*)Bs + off;
    const size_t rowskip = (size_t)64 * K;

    f32x4 acc[4][4] = {};

    const int l16 = lane & 15;
    const int kb  = (lane >> 4) * 8;  // k element base for this lane

    for (int k0 = 0; k0 < K; k0 += 32) {
        async16(AsD,        Ag + k0);
        async16(AsD + 4096, Ag + rowskip + k0);
        async16(BsD,        Bg + k0);
        async16(BsD + 4096, Bg + rowskip + k0);
        __syncthreads();   // compiler drains vmcnt before s_barrier

        half8 af[4], bf[4];
#pragma unroll
        for (int m = 0; m < 4; ++m)
            af[m] = *(const half8*)&As[(wr * 64 + m * 16 + l16) * 32 + kb];
#pragma unroll
        for (int n = 0; n < 4; ++n)
            bf[n] = *(const half8*)&Bs[(wc * 64 + n * 16 + l16) * 32 + kb];
#pragma unroll
        for (int m = 0; m < 4; ++m)
#pragma unroll
            for (int n = 0; n < 4; ++n)
                acc[m][n] = __builtin_amdgcn_mfma_f32_16x16x32_f16(
                    af[m], bf[n], acc[m][n], 0, 0, 0);
        __syncthreads();
    }

    // epilogue: C/D layout col=lane&15, row=(lane>>4)*4+reg
    const int rbase = m0 + wr * 64 + (lane >> 4) * 4;
#pragma unroll
    for (int n = 0; n < 4; ++n) {
        const int col = n0 + wc * 64 + n * 16 + l16;
        float bb = 0.f;
        if (BIAS) bb = bias[col];
#pragma unroll
        for (int m = 0; m < 4; ++m) {
            f32x4 v = acc[m][n];
#pragma unroll
            for (int j = 0; j < 4; ++j) {
                float o = v[j] + bb;
                if (RELU) o = fmaxf(o, 0.f);
                const size_t idx = (size_t)(rbase + m * 16 + j) * N + col;
                if constexpr (sizeof(OutT) == 2)
                    ((unsigned short*)C)[idx] = f2h(o);
                else
                    ((float*)C)[idx] = o;
            }
        }
    }
}

// ---------------------------------------------------------------- softmax
// scores [rows, 2048] f32 -> alpha fp16, masked positions -> 0
// mask base is pre-offset to this chunk; local batch = row>>11.
__global__ __launch_bounds__(256) void masked_softmax_kernel(
    const float* __restrict__ scores,
    const unsigned char* __restrict__ mask,
    unsigned short* __restrict__ alpha)
{
    const int row = blockIdx.x;
    const int bl  = row >> 11;           // local batch
    const float* s = scores + (size_t)row * 2048;
    unsigned short* a = alpha + (size_t)row * 2048;
    const unsigned char* mk = mask + (bl << 11);
    const int t = threadIdx.x;

    float v[8]; int m[8];
    float mx = -1e30f;
#pragma unroll
    for (int r = 0; r < 8; ++r) {
        const int j = (r << 8) + t;
        v[r] = s[j];
        m[r] = mk[j];
        if (!m[r]) mx = fmaxf(mx, v[r]);
    }
    for (int o = 32; o > 0; o >>= 1) mx = fmaxf(mx, __shfl_xor(mx, o));
    __shared__ float red[4];
    const int lane = t & 63, wave = t >> 6;
    if (lane == 0) red[wave] = mx;
    __syncthreads();
    mx = fmaxf(fmaxf(red[0], red[1]), fmaxf(red[2], red[3]));

    float e[8];
    float sum = 0.f;
#pragma unroll
    for (int r = 0; r < 8; ++r) {
        e[r] = m[r] ? 0.f : __expf(v[r] - mx);
        sum += e[r];
    }
    for (int o = 32; o > 0; o >>= 1) sum += __shfl_xor(sum, o);
    __shared__ float red2[4];
    if (lane == 0) red2[wave] = sum;
    __syncthreads();
    sum = red2[0] + red2[1] + red2[2] + red2[3];
    const float inv = 1.f / sum;
#pragma unroll
    for (int r = 0; r < 8; ++r) {
        const int j = (r << 8) + t;
        a[j] = f2h(e[r] * inv);
    }
}

// ---------------------------------------------------------------- launch
extern "C" void kernel_launch(void* const* d_in, const int* in_sizes, int n_in,
                              void* d_out, int out_size, void* d_ws, size_t ws_size,
                              hipStream_t stream)
{
    const float* x  = (const float*)d_in[0];
    const float* y  = (const float*)d_in[1];
    const float* W1 = (const float*)d_in[2];
    const float* b1 = (const float*)d_in[3];
    const float* W2 = (const float*)d_in[4];
    const float* b2 = (const float*)d_in[5];
    const unsigned char* ymask_raw = (const unsigned char*)d_in[6];

    constexpr int B = 8, L1 = 2048, L2 = 2048, H = 1024;
    constexpr size_t NXH = (size_t)B * L1 * H;   // 16.7M elements
    constexpr size_t NW  = (size_t)H * H;

    // ---- workspace layout (~172 MB total) ----
    // [xh | yh] (67 MB, dead after proj+transpose; reused as sc+al per chunk)
    // [w1h][w2h][xp][yp][yT][mk]
    char* ws = (char*)d_ws;
    unsigned short* xh  = (unsigned short*)ws;  ws += NXH * 2;       // 33.5 MB
    unsigned short* yh  = (unsigned short*)ws;  ws += NXH * 2;       // 33.5 MB
    unsigned short* w1h = (unsigned short*)ws;  ws += NW * 2;        //  2 MB
    unsigned short* w2h = (unsigned short*)ws;  ws += NW * 2;        //  2 MB
    unsigned short* xp  = (unsigned short*)ws;  ws += NXH * 2;       // 33.5 MB
    unsigned short* yp  = (unsigned short*)ws;  ws += NXH * 2;       // 33.5 MB
    unsigned short* yT  = (unsigned short*)ws;  ws += NXH * 2;       // 33.5 MB
    unsigned char*  mk  = (unsigned char*)ws;   ws += B * L2;        // 16 KB
    // per-chunk (2 batches) overlay on [xh|yh]:
    float*          sc = (float*)xh;                         // 2*L1*L2*4 = 33.5 MB
    unsigned short* al = (unsigned short*)((char*)xh + (size_t)2 * L1 * L2 * 4); // 16.8 MB

    cvt_f32_f16_kernel<<<(int)(NXH / 4 / 256), 256, 0, stream>>>(
        (const float4*)x, (ushort4*)xh, (int)(NXH / 4));
    cvt_f32_f16_kernel<<<(int)(NXH / 4 / 256), 256, 0, stream>>>(
        (const float4*)y, (ushort4*)yh, (int)(NXH / 4));
    cvt_f32_f16_kernel<<<(int)(NW / 4 / 256), 256, 0, stream>>>(
        (const float4*)W1, (ushort4*)w1h, (int)(NW / 4));
    cvt_f32_f16_kernel<<<(int)(NW / 4 / 256), 256, 0, stream>>>(
        (const float4*)W2, (ushort4*)w2h, (int)(NW / 4));
    mask_prep_kernel<<<1, 256, 0, stream>>>(ymask_raw, mk);

    // x_proj = relu(x @ W1^T + b1): M=B*L1=16384, N=1024, K=1024
    dim3 gProj(16384 / 128, 1024 / 128, 1);
    gemm_bt_kernel<unsigned short, true, true><<<gProj, 256, 0, stream>>>(
        xh, w1h, xp, b1, H, H, 0, 0, 0);
    gemm_bt_kernel<unsigned short, true, true><<<gProj, 256, 0, stream>>>(
        yh, w2h, yp, b2, H, H, 0, 0, 0);

    transpose_kernel<<<dim3(L2 / 64, H / 64, B), 256, 0, stream>>>(yh, yT);
    // xh, yh are now dead -> sc/al overlay is safe from here on.

    for (int c0 = 0; c0 < B; c0 += 2) {
        // scores = x_proj @ y_proj^T : M=2048, N=2048, K=1024, z=2 batches
        dim3 gSc(L1 / 128, L2 / 128, 2);
        gemm_bt_kernel<float, false, false><<<gSc, 256, 0, stream>>>(
            xp + (size_t)c0 * L1 * H, yp + (size_t)c0 * L2 * H, sc, nullptr,
            H, L2, (long long)L1 * H, (long long)L2 * H, (long long)L1 * L2);

        masked_softmax_kernel<<<2 * L1, 256, 0, stream>>>(
            sc, mk + (size_t)c0 * L2, al);

        // out = alpha @ y = alpha @ yT^T : M=2048, N=1024, K=2048, z=2
        dim3 gOut(L1 / 128, H / 128, 2);
        gemm_bt_kernel<float, false, false><<<gOut, 256, 0, stream>>>(
            al, yT + (size_t)c0 * H * L2, (float*)d_out + (size_t)c0 * L1 * H,
            nullptr, L2, H,
            (long long)L1 * L2, (long long)H * L2, (long long)L1 * H);
    }
}

// Round 3
// 563.636 us; speedup vs baseline: 1.2425x; 1.2425x over previous
//
#include <hip/hip_runtime.h>
#include <hip/hip_fp16.h>

// SeqAttnMatch: B=8, L1=2048, L2=2048, H=1024
//   x_proj = relu(x @ W1^T + b1); y_proj = relu(y @ W2^T + b2)
//   scores = x_proj @ y_proj^T; mask; softmax over L2; out = alpha @ y
// fp16 MFMA GEMMs (f32 accum). alpha is written fp16 IN-PLACE over the f32
// score rows (lda 4096), so the score buffer needs no alpha sibling.
// Layout A (ws >= 239MB): all 8 batches in one scores/PV launch.
// Layout B (fallback, 172MB): 2 chunks of 4 batches.

using half8 = __attribute__((ext_vector_type(8))) _Float16;
using f32x4 = __attribute__((ext_vector_type(4))) float;

#define DEVI __device__ __forceinline__

DEVI void async16(void* lds, const void* g) {
    __builtin_amdgcn_global_load_lds(
        (const __attribute__((address_space(1))) unsigned int*)g,
        (__attribute__((address_space(3))) unsigned int*)lds,
        16, 0, 0);
}

DEVI unsigned short f2h(float f) { return __half_as_ushort(__float2half(f)); }

// ---------------------------------------------------------------- converts
__global__ __launch_bounds__(256) void cvt_f32_f16_kernel(
    const float4* __restrict__ in, ushort4* __restrict__ out, int n4)
{
    int i = blockIdx.x * 256 + threadIdx.x;
    if (i >= n4) return;
    float4 f = in[i];
    ushort4 o;
    o.x = f2h(f.x); o.y = f2h(f.y); o.z = f2h(f.z); o.w = f2h(f.w);
    out[i] = o;
}

// ---------------------------------------------------------------- mask decode
// y_mask bool[8][2048]; may arrive as uint8/int32/f32. Classify by byte-lane
// stats over the first 16384 bytes (valid reads for every candidate dtype).
__global__ void mask_prep_kernel(const unsigned char* __restrict__ raw,
                                 unsigned char* __restrict__ mask)
{
    __shared__ int S0, S123;
    const int t = threadIdx.x;
    if (t == 0) { S0 = 0; S123 = 0; }
    __syncthreads();
    int s0 = 0, s123 = 0;
    for (int i = t; i < 16384; i += 256) {
        int v = raw[i];
        if ((i & 3) == 0) s0 += v; else s123 += v;
    }
    atomicAdd(&S0, s0); atomicAdd(&S123, s123);
    __syncthreads();
    const int mode = (S123 == 0) ? 1 : ((S0 == 0) ? 2 : 0);
    for (int i = t; i < 16384; i += 256) {
        unsigned char m;
        if (mode == 0)      m = raw[i] ? 1 : 0;
        else if (mode == 1) m = ((const int*)raw)[i] ? 1 : 0;
        else                m = (((const float*)raw)[i] != 0.f) ? 1 : 0;
        mask[i] = m;
    }
}

// ---------------------------------------------------------------- transpose
// yh [B, L2, H] fp16 -> yT [B, H, L2] fp16
__global__ __launch_bounds__(256) void transpose_kernel(
    const unsigned short* __restrict__ y, unsigned short* __restrict__ yT)
{
    const int b  = blockIdx.z;
    const int i0 = blockIdx.x * 64;
    const int h0 = blockIdx.y * 64;
    __shared__ unsigned short tile[64][72];
    const int t  = threadIdx.x;
    const int tr = t >> 4;
    const int tc = (t & 15) * 4;
    const size_t ybase = ((size_t)b * 2048 + i0) * 1024 + h0;
#pragma unroll
    for (int p = 0; p < 4; ++p) {
        const int r = p * 16 + tr;
        ushort4 v = *(const ushort4*)(y + ybase + (size_t)r * 1024 + tc);
        *(ushort4*)&tile[r][tc] = v;
    }
    __syncthreads();
    const size_t obase = ((size_t)b * 1024 + h0) * 2048 + i0;
#pragma unroll
    for (int p = 0; p < 4; ++p) {
        const int r = p * 16 + tr;
        ushort4 v;
        v.x = tile[tc + 0][r]; v.y = tile[tc + 1][r];
        v.z = tile[tc + 2][r]; v.w = tile[tc + 3][r];
        *(ushort4*)(yT + obase + (size_t)r * 2048 + tc) = v;
    }
}

// ---------------------------------------------------------------- GEMM body
// C[m,n] = act( sum_k A[m,k] * Bt[n,k] + bias[n] ), fp16 in, f32 accum.
// m97 structure: 128x128 tile, BK=32, 4 waves (2x2 of 64x64),
// global_load_lds width 16, mfma_f32_16x16x32_f16. ldb == K.
template<typename OutT, bool RELU, bool BIAS>
DEVI void gemm_bt_body(unsigned short* As, unsigned short* Bs,
                       const unsigned short* __restrict__ A, int lda,
                       const unsigned short* __restrict__ Bt,
                       OutT* __restrict__ C, int ldc,
                       const float* __restrict__ bias, int K,
                       int m0, int n0)
{
    const int t    = threadIdx.x;
    const int lane = t & 63;
    const int wave = t >> 6;
    const int wr   = wave >> 1;
    const int wc   = wave & 1;

    const int off  = t * 16;          // byte offset in LDS chunk
    const int srow = off >> 6;        // 64B per row (32 fp16)
    const int scb  = off & 63;
    const unsigned short* Ag = A + (size_t)(m0 + srow) * lda + (scb >> 1);
    const unsigned short* Bg = Bt + (size_t)(n0 + srow) * K + (scb >> 1);
    char* AsD = (char*)As + off;
    char* BsD = (char*)Bs + off;
    const size_t rowskipA = (size_t)64 * lda;
    const size_t rowskipB = (size_t)64 * K;

    f32x4 acc[4][4] = {};

    const int l16 = lane & 15;
    const int kb  = (lane >> 4) * 8;

    for (int k0 = 0; k0 < K; k0 += 32) {
        async16(AsD,        Ag + k0);
        async16(AsD + 4096, Ag + rowskipA + k0);
        async16(BsD,        Bg + k0);
        async16(BsD + 4096, Bg + rowskipB + k0);
        __syncthreads();

        half8 af[4], bf[4];
#pragma unroll
        for (int m = 0; m < 4; ++m)
            af[m] = *(const half8*)&As[(wr * 64 + m * 16 + l16) * 32 + kb];
#pragma unroll
        for (int n = 0; n < 4; ++n)
            bf[n] = *(const half8*)&Bs[(wc * 64 + n * 16 + l16) * 32 + kb];
#pragma unroll
        for (int m = 0; m < 4; ++m)
#pragma unroll
            for (int n = 0; n < 4; ++n)
                acc[m][n] = __builtin_amdgcn_mfma_f32_16x16x32_f16(
                    af[m], bf[n], acc[m][n], 0, 0, 0);
        __syncthreads();
    }

    // epilogue: C/D layout col=lane&15, row=(lane>>4)*4+reg
    const int rbase = m0 + wr * 64 + (lane >> 4) * 4;
#pragma unroll
    for (int n = 0; n < 4; ++n) {
        const int col = n0 + wc * 64 + n * 16 + l16;
        float bb = 0.f;
        if (BIAS) bb = bias[col];
#pragma unroll
        for (int m = 0; m < 4; ++m) {
            f32x4 v = acc[m][n];
#pragma unroll
            for (int j = 0; j < 4; ++j) {
                float o = v[j] + bb;
                if (RELU) o = fmaxf(o, 0.f);
                const size_t idx = (size_t)(rbase + m * 16 + j) * ldc + col;
                if constexpr (sizeof(OutT) == 2)
                    ((unsigned short*)C)[idx] = f2h(o);
                else
                    ((float*)C)[idx] = o;
            }
        }
    }
}

// generic batched GEMM (z = batch)
template<typename OutT, bool RELU, bool BIAS>
__global__ __launch_bounds__(256) void gemm_bt_kernel(
    const unsigned short* __restrict__ A, int lda, long long sA,
    const unsigned short* __restrict__ Bt, long long sB,
    OutT* __restrict__ C, int ldc, long long sC,
    const float* __restrict__ bias, int K)
{
    __shared__ __align__(16) unsigned short As[128 * 32];
    __shared__ __align__(16) unsigned short Bs[128 * 32];
    const int b = blockIdx.z;
    gemm_bt_body<OutT, RELU, BIAS>(As, Bs,
        A + (size_t)b * sA, lda, Bt + (size_t)b * sB,
        C + (size_t)b * sC, ldc, bias, K,
        blockIdx.x * 128, blockIdx.y * 128);
}

// merged projections: z=0 -> x@W1, z=1 -> y@W2 (uniform branch per block)
__global__ __launch_bounds__(256) void proj_gemm_kernel(
    const unsigned short* __restrict__ xh, const unsigned short* __restrict__ yh,
    const unsigned short* __restrict__ w1, const unsigned short* __restrict__ w2,
    const float* __restrict__ b1, const float* __restrict__ b2,
    unsigned short* __restrict__ xp, unsigned short* __restrict__ yp)
{
    __shared__ __align__(16) unsigned short As[128 * 32];
    __shared__ __align__(16) unsigned short Bs[128 * 32];
    const bool sel = blockIdx.z != 0;
    gemm_bt_body<unsigned short, true, true>(As, Bs,
        sel ? yh : xh, 1024, sel ? w2 : w1,
        sel ? yp : xp, 1024, sel ? b2 : b1, 1024,
        blockIdx.x * 128, blockIdx.y * 128);
}

// ---------------------------------------------------------------- softmax
// scores [rows, ld 2048] f32 -> alpha fp16 written IN-PLACE at row stride
// lda_out (4096 elems = same byte base as the f32 row). All reads complete
// before the last __syncthreads; writes after it; blocks touch disjoint rows.
__global__ __launch_bounds__(256) void masked_softmax_kernel(
    const float* __restrict__ scores,
    const unsigned char* __restrict__ mask,
    unsigned short* __restrict__ alpha, int lda_out)
{
    const int row = blockIdx.x;
    const int bl  = row >> 11;           // batch within this launch
    const float* s = scores + (size_t)row * 2048;
    unsigned short* a = alpha + (size_t)row * lda_out;
    const unsigned char* mk = mask + (bl << 11);
    const int t = threadIdx.x;

    float v[8]; int m[8];
    float mx = -1e30f;
#pragma unroll
    for (int r = 0; r < 8; ++r) {
        const int j = (r << 8) + t;
        v[r] = s[j];
        m[r] = mk[j];
        if (!m[r]) mx = fmaxf(mx, v[r]);
    }
    for (int o = 32; o > 0; o >>= 1) mx = fmaxf(mx, __shfl_xor(mx, o));
    __shared__ float red[4];
    const int lane = t & 63, wave = t >> 6;
    if (lane == 0) red[wave] = mx;
    __syncthreads();
    mx = fmaxf(fmaxf(red[0], red[1]), fmaxf(red[2], red[3]));

    float e[8];
    float sum = 0.f;
#pragma unroll
    for (int r = 0; r < 8; ++r) {
        e[r] = m[r] ? 0.f : __expf(v[r] - mx);
        sum += e[r];
    }
    for (int o = 32; o > 0; o >>= 1) sum += __shfl_xor(sum, o);
    __shared__ float red2[4];
    if (lane == 0) red2[wave] = sum;
    __syncthreads();
    sum = red2[0] + red2[1] + red2[2] + red2[3];
    const float inv = 1.f / sum;
#pragma unroll
    for (int r = 0; r < 8; ++r) {
        const int j = (r << 8) + t;
        a[j] = f2h(e[r] * inv);
    }
}

// ---------------------------------------------------------------- launch
extern "C" void kernel_launch(void* const* d_in, const int* in_sizes, int n_in,
                              void* d_out, int out_size, void* d_ws, size_t ws_size,
                              hipStream_t stream)
{
    const float* x  = (const float*)d_in[0];
    const float* y  = (const float*)d_in[1];
    const float* W1 = (const float*)d_in[2];
    const float* b1 = (const float*)d_in[3];
    const float* W2 = (const float*)d_in[4];
    const float* b2 = (const float*)d_in[5];
    const unsigned char* ymask_raw = (const unsigned char*)d_in[6];

    constexpr int B = 8, L1 = 2048, L2 = 2048, H = 1024;
    constexpr size_t NXH   = (size_t)B * L1 * H;          // 16.7M elems
    constexpr size_t NW    = (size_t)H * H;
    constexpr size_t SC_B8 = (size_t)B * L1 * L2 * 4;     // 134 MB (8 batches)
    constexpr size_t SC_B4 = SC_B8 / 2;                   // 67 MB  (4 batches)
    constexpr size_t FIXED = 2 * NW * 2 + 3 * NXH * 2 + B * L2; // w1h+w2h+xp+yp+yT+mk

    const bool big = ws_size >= SC_B8 + FIXED;            // ~239 MB needed
    const size_t sc_bytes = big ? SC_B8 : SC_B4;

    // [sc (>= xh+yh overlay)] [w1h][w2h][xp][yp][yT][mk]
    char* ws = (char*)d_ws;
    float*          sc  = (float*)ws;           ws += sc_bytes;
    unsigned short* w1h = (unsigned short*)ws;  ws += NW * 2;
    unsigned short* w2h = (unsigned short*)ws;  ws += NW * 2;
    unsigned short* xp  = (unsigned short*)ws;  ws += NXH * 2;
    unsigned short* yp  = (unsigned short*)ws;  ws += NXH * 2;
    unsigned short* yT  = (unsigned short*)ws;  ws += NXH * 2;
    unsigned char*  mk  = (unsigned char*)ws;   ws += B * L2;
    // xh/yh overlay the score buffer (dead once scores GEMM starts)
    unsigned short* xh = (unsigned short*)sc;
    unsigned short* yh = xh + NXH;

    cvt_f32_f16_kernel<<<(int)(NXH / 4 / 256), 256, 0, stream>>>(
        (const float4*)x, (ushort4*)xh, (int)(NXH / 4));
    cvt_f32_f16_kernel<<<(int)(NXH / 4 / 256), 256, 0, stream>>>(
        (const float4*)y, (ushort4*)yh, (int)(NXH / 4));
    cvt_f32_f16_kernel<<<(int)(NW / 4 / 256), 256, 0, stream>>>(
        (const float4*)W1, (ushort4*)w1h, (int)(NW / 4));
    cvt_f32_f16_kernel<<<(int)(NW / 4 / 256), 256, 0, stream>>>(
        (const float4*)W2, (ushort4*)w2h, (int)(NW / 4));
    mask_prep_kernel<<<1, 256, 0, stream>>>(ymask_raw, mk);

    // merged projections: M=16384, N=1024, K=1024; 2048 blocks
    proj_gemm_kernel<<<dim3(16384 / 128, 1024 / 128, 2), 256, 0, stream>>>(
        xh, yh, w1h, w2h, b1, b2, xp, yp);

    transpose_kernel<<<dim3(L2 / 64, H / 64, B), 256, 0, stream>>>(yh, yT);
    // xh/yh dead from here; sc overlay live.

    const int CB = big ? B : 4;                 // batches per chunk
    for (int c0 = 0; c0 < B; c0 += CB) {
        float*          scc = sc;               // chunk score base (reused)
        unsigned short* al  = (unsigned short*)sc;  // fp16 alpha, lda 4096

        // scores = x_proj @ y_proj^T : M=2048, N=2048, K=1024
        gemm_bt_kernel<float, false, false>
            <<<dim3(L1 / 128, L2 / 128, CB), 256, 0, stream>>>(
            xp + (size_t)c0 * L1 * H, H, (long long)L1 * H,
            yp + (size_t)c0 * L2 * H, (long long)L2 * H,
            scc, L2, (long long)L1 * L2, nullptr, H);

        masked_softmax_kernel<<<CB * L1, 256, 0, stream>>>(
            scc, mk + (size_t)c0 * L2, al, 2 * L2);

        // out = alpha @ yT^T : M=2048, N=1024, K=2048 (lda 4096)
        gemm_bt_kernel<float, false, false>
            <<<dim3(L1 / 128, H / 128, CB), 256, 0, stream>>>(
            al, 2 * L2, (long long)L1 * 2 * L2,
            yT + (size_t)c0 * H * L2, (long long)H * L2,
            (float*)d_out + (size_t)c0 * L1 * H, H, (long long)L1 * H,
            nullptr, L2);
    }
}

// Round 4
// 499.830 us; speedup vs baseline: 1.4011x; 1.1277x over previous
//
#include <hip/hip_runtime.h>
#include <hip/hip_fp16.h>

// SeqAttnMatch: B=8, L1=2048, L2=2048, H=1024
//   x_proj = relu(x @ W1^T + b1); y_proj = relu(y @ W2^T + b2)
//   scores = x_proj @ y_proj^T; mask; softmax over L2; out = alpha @ y
// GEMMs: 256x256 tile, 8 waves, BK=32, 4-buffer LDS pipeline with counted
// vmcnt across raw barriers (T3+T4), T2 XOR-swizzle (pre-swizzled global
// source + swizzled ds_read), T5 setprio. fp16 MFMA 16x16x32, f32 accum.

using half8 = __attribute__((ext_vector_type(8))) _Float16;
using f32x4 = __attribute__((ext_vector_type(4))) float;

#define DEVI __device__ __forceinline__

DEVI void async16(void* lds, const void* g) {
    __builtin_amdgcn_global_load_lds(
        (const __attribute__((address_space(1))) unsigned int*)g,
        (__attribute__((address_space(3))) unsigned int*)lds,
        16, 0, 0);
}

DEVI unsigned short f2h(float f) { return __half_as_ushort(__float2half(f)); }

// ---------------------------------------------------------------- converts
__global__ __launch_bounds__(256) void cvt_f32_f16_kernel(
    const float4* __restrict__ in, ushort4* __restrict__ out, int n4)
{
    int i = blockIdx.x * 256 + threadIdx.x;
    if (i >= n4) return;
    float4 f = in[i];
    ushort4 o;
    o.x = f2h(f.x); o.y = f2h(f.y); o.z = f2h(f.z); o.w = f2h(f.w);
    out[i] = o;
}

// ---------------------------------------------------------------- mask decode
// y_mask bool[8][2048]; may arrive as uint8/int32/f32. Classify by byte-lane
// stats over the first 16384 bytes (valid reads for every candidate dtype).
__global__ void mask_prep_kernel(const unsigned char* __restrict__ raw,
                                 unsigned char* __restrict__ mask)
{
    __shared__ int S0, S123;
    const int t = threadIdx.x;
    if (t == 0) { S0 = 0; S123 = 0; }
    __syncthreads();
    int s0 = 0, s123 = 0;
    for (int i = t; i < 16384; i += 256) {
        int v = raw[i];
        if ((i & 3) == 0) s0 += v; else s123 += v;
    }
    atomicAdd(&S0, s0); atomicAdd(&S123, s123);
    __syncthreads();
    const int mode = (S123 == 0) ? 1 : ((S0 == 0) ? 2 : 0);
    for (int i = t; i < 16384; i += 256) {
        unsigned char m;
        if (mode == 0)      m = raw[i] ? 1 : 0;
        else if (mode == 1) m = ((const int*)raw)[i] ? 1 : 0;
        else                m = (((const float*)raw)[i] != 0.f) ? 1 : 0;
        mask[i] = m;
    }
}

// ---------------------------------------------------------------- transpose+cvt
// y f32 [B, L2, H] -> yh fp16 [B, L2, H] and yT fp16 [B, H, L2]
__global__ __launch_bounds__(256) void transpose_cvt_kernel(
    const float* __restrict__ y, unsigned short* __restrict__ yh,
    unsigned short* __restrict__ yT)
{
    const int b  = blockIdx.z;
    const int i0 = blockIdx.x * 64;   // L2 tile
    const int h0 = blockIdx.y * 64;   // H tile
    __shared__ unsigned short tile[64][72];
    const int t  = threadIdx.x;
    const int tr = t >> 4;            // 0..15
    const int tc = (t & 15) * 4;      // 0..60
    const size_t ybase = ((size_t)b * 2048 + i0) * 1024 + h0;
#pragma unroll
    for (int p = 0; p < 4; ++p) {
        const int r = p * 16 + tr;
        float4 f = *(const float4*)(y + ybase + (size_t)r * 1024 + tc);
        ushort4 v;
        v.x = f2h(f.x); v.y = f2h(f.y); v.z = f2h(f.z); v.w = f2h(f.w);
        *(ushort4*)(yh + ybase + (size_t)r * 1024 + tc) = v;
        *(ushort4*)&tile[r][tc] = v;
    }
    __syncthreads();
    const size_t obase = ((size_t)b * 1024 + h0) * 2048 + i0;
#pragma unroll
    for (int p = 0; p < 4; ++p) {
        const int r = p * 16 + tr;
        ushort4 v;
        v.x = tile[tc + 0][r]; v.y = tile[tc + 1][r];
        v.z = tile[tc + 2][r]; v.w = tile[tc + 3][r];
        *(ushort4*)(yT + obase + (size_t)r * 2048 + tc) = v;
    }
}

// ---------------------------------------------------------------- GEMM 256x256
// C[m,n] = act( sum_k A[m,k] * Bt[n,k] + bias[n] ), fp16 in, f32 accum.
// 8 waves (2Mx4N), per-wave 128x64 out, BK=32, 4 LDS buffers (128 KiB dyn),
// depth-3 prefetch, counted vmcnt(8) across raw barriers, T2 swizzle, T5.
template<typename OutT, bool RELU, bool BIAS>
DEVI void gemm256_body(unsigned short* lds,
                       const unsigned short* __restrict__ A, int lda,
                       const unsigned short* __restrict__ Bt, int ldb,
                       OutT* __restrict__ C, int ldc,
                       const float* __restrict__ bias, int K,
                       int m0, int n0)
{
    const int t    = threadIdx.x;     // 0..511
    const int lane = t & 63;
    const int wave = t >> 6;          // 0..7
    const int wr   = wave >> 2;       // 0..1  (M half)
    const int wc   = wave & 3;        // 0..3  (N quarter)
    const int l16  = lane & 15;
    const int q    = lane >> 4;       // 0..3

    // ---- staging precompute: thread t covers LDS bytes o0 and o1 of each
    // 16KB tile (A at buf+0, B at buf+16384). Global source is pre-swizzled
    // by the same XOR the reader applies (involution, rule: linear LDS dest).
    const int o0 = t * 16;
    const int o1 = o0 + 8192;
    const int r0 = o0 >> 6;           // row (64B per row = 32 fp16)
    const int r1 = o1 >> 6;
    const int s0 = (o0 & 63) ^ ((r0 & 3) << 4);
    const int s1 = (o1 & 63) ^ ((r1 & 3) << 4);
    const unsigned short* Ag0 = A + (size_t)(m0 + r0) * lda + (s0 >> 1);
    const unsigned short* Ag1 = A + (size_t)(m0 + r1) * lda + (s1 >> 1);
    const unsigned short* Bg0 = Bt + (size_t)(n0 + r0) * ldb + (s0 >> 1);
    const unsigned short* Bg1 = Bt + (size_t)(n0 + r1) * ldb + (s1 >> 1);

#define STAGE256(bufi, kt) do {                                   \
        char* dst = (char*)lds + (size_t)(bufi) * 32768;          \
        const size_t ko = (size_t)(kt) * 32;                      \
        async16(dst + o0,         Ag0 + ko);                      \
        async16(dst + o1,         Ag1 + ko);                      \
        async16(dst + 16384 + o0, Bg0 + ko);                      \
        async16(dst + 16384 + o1, Bg1 + ko);                      \
    } while (0)

    // ---- fragment read offsets (swizzled)
    const int swz  = (l16 & 3) << 4;
    const int aoff = (wr * 128 + l16) * 64 + ((q * 16) ^ swz);
    const int boff = 16384 + (wc * 64 + l16) * 64 + ((q * 16) ^ swz);

    f32x4 acc[8][4] = {};

    const int NT = K >> 5;            // BK=32 tiles (NT >= 32 for our shapes)

    STAGE256(0, 0); STAGE256(1, 1); STAGE256(2, 2);   // 12 in flight
    asm volatile("s_waitcnt vmcnt(8)" ::: "memory");  // tile 0 landed
    __builtin_amdgcn_s_barrier();

    for (int tt = 0; tt < NT; ++tt) {
        const int c = tt & 3;
        const bool more = (tt + 3) < NT;
        if (more) STAGE256((tt + 3) & 3, tt + 3);     // issue early (hides HBM)

        const char* bufp = (const char*)lds + (size_t)c * 32768;
        half8 af[8], bf[4];
#pragma unroll
        for (int m = 0; m < 8; ++m)
            af[m] = *(const half8*)(bufp + aoff + m * 1024);
#pragma unroll
        for (int n = 0; n < 4; ++n)
            bf[n] = *(const half8*)(bufp + boff + n * 1024);

        __builtin_amdgcn_s_setprio(1);
#pragma unroll
        for (int m = 0; m < 8; ++m)
#pragma unroll
            for (int n = 0; n < 4; ++n)
                acc[m][n] = __builtin_amdgcn_mfma_f32_16x16x32_f16(
                    af[m], bf[n], acc[m][n], 0, 0, 0);
        __builtin_amdgcn_s_setprio(0);

        // wave passes barrier only once ITS tile-(tt+1) loads are landed;
        // all waves past barrier => buffer fully written. Never drains to 0
        // in steady state (tiles tt+2, tt+3 stay in flight).
        if (more)              asm volatile("s_waitcnt vmcnt(8)" ::: "memory");
        else if (tt + 2 < NT)  asm volatile("s_waitcnt vmcnt(4)" ::: "memory");
        else                   asm volatile("s_waitcnt vmcnt(0)" ::: "memory");
        __builtin_amdgcn_s_barrier();
    }
#undef STAGE256

    // ---- epilogue: C/D layout col=lane&15, row=(lane>>4)*4+j
    const int rb = m0 + wr * 128 + q * 4;
#pragma unroll
    for (int n = 0; n < 4; ++n) {
        const int col = n0 + wc * 64 + n * 16 + l16;
        float bb = 0.f;
        if (BIAS) bb = bias[col];
#pragma unroll
        for (int m = 0; m < 8; ++m) {
#pragma unroll
            for (int j = 0; j < 4; ++j) {
                float o = acc[m][n][j] + bb;
                if (RELU) o = fmaxf(o, 0.f);
                const size_t idx = (size_t)(rb + m * 16 + j) * ldc + col;
                if constexpr (sizeof(OutT) == 2)
                    ((unsigned short*)C)[idx] = f2h(o);
                else
                    ((float*)C)[idx] = o;
            }
        }
    }
}

template<typename OutT, bool RELU, bool BIAS>
__global__ __launch_bounds__(512, 2) void gemm256_kernel(
    const unsigned short* __restrict__ A, int lda, long long sA,
    const unsigned short* __restrict__ Bt, int ldb, long long sB,
    OutT* __restrict__ C, int ldc, long long sC,
    const float* __restrict__ bias, int K)
{
    extern __shared__ unsigned short lds[];   // 131072 B (4 buffers x 32 KB)
    const int b = blockIdx.z;
    gemm256_body<OutT, RELU, BIAS>(lds,
        A + (size_t)b * sA, lda, Bt + (size_t)b * sB, ldb,
        C + (size_t)b * sC, ldc, bias, K,
        blockIdx.x * 256, blockIdx.y * 256);
}

// merged projections: z=0 -> x@W1, z=1 -> y@W2 (uniform select)
__global__ __launch_bounds__(512, 2) void proj256_kernel(
    const unsigned short* __restrict__ xh, const unsigned short* __restrict__ yh,
    const unsigned short* __restrict__ w1, const unsigned short* __restrict__ w2,
    const float* __restrict__ b1, const float* __restrict__ b2,
    unsigned short* __restrict__ xp, unsigned short* __restrict__ yp)
{
    extern __shared__ unsigned short lds[];
    const bool sel = blockIdx.z != 0;
    gemm256_body<unsigned short, true, true>(lds,
        sel ? yh : xh, 1024, sel ? w2 : w1, 1024,
        sel ? yp : xp, 1024, sel ? b2 : b1, 1024,
        blockIdx.x * 256, blockIdx.y * 256);
}

// ---------------------------------------------------------------- softmax
// scores [rows, ld 2048] f32 -> alpha fp16 written IN-PLACE at row stride
// lda_out (4096 elems = same byte base as the f32 row).
__global__ __launch_bounds__(256) void masked_softmax_kernel(
    const float* __restrict__ scores,
    const unsigned char* __restrict__ mask,
    unsigned short* __restrict__ alpha, int lda_out)
{
    const int row = blockIdx.x;
    const int bl  = row >> 11;           // batch within this launch
    const float* s = scores + (size_t)row * 2048;
    unsigned short* a = alpha + (size_t)row * lda_out;
    const unsigned char* mk = mask + (bl << 11);
    const int t = threadIdx.x;

    float v[8]; int m[8];
    float mx = -1e30f;
#pragma unroll
    for (int r = 0; r < 8; ++r) {
        const int j = (r << 8) + t;
        v[r] = s[j];
        m[r] = mk[j];
        if (!m[r]) mx = fmaxf(mx, v[r]);
    }
    for (int o = 32; o > 0; o >>= 1) mx = fmaxf(mx, __shfl_xor(mx, o));
    __shared__ float red[4];
    const int lane = t & 63, wave = t >> 6;
    if (lane == 0) red[wave] = mx;
    __syncthreads();
    mx = fmaxf(fmaxf(red[0], red[1]), fmaxf(red[2], red[3]));

    float e[8];
    float sum = 0.f;
#pragma unroll
    for (int r = 0; r < 8; ++r) {
        e[r] = m[r] ? 0.f : __expf(v[r] - mx);
        sum += e[r];
    }
    for (int o = 32; o > 0; o >>= 1) sum += __shfl_xor(sum, o);
    __shared__ float red2[4];
    if (lane == 0) red2[wave] = sum;
    __syncthreads();
    sum = red2[0] + red2[1] + red2[2] + red2[3];
    const float inv = 1.f / sum;
#pragma unroll
    for (int r = 0; r < 8; ++r) {
        const int j = (r << 8) + t;
        a[j] = f2h(e[r] * inv);
    }
}

// ---------------------------------------------------------------- launch
extern "C" void kernel_launch(void* const* d_in, const int* in_sizes, int n_in,
                              void* d_out, int out_size, void* d_ws, size_t ws_size,
                              hipStream_t stream)
{
    const float* x  = (const float*)d_in[0];
    const float* y  = (const float*)d_in[1];
    const float* W1 = (const float*)d_in[2];
    const float* b1 = (const float*)d_in[3];
    const float* W2 = (const float*)d_in[4];
    const float* b2 = (const float*)d_in[5];
    const unsigned char* ymask_raw = (const unsigned char*)d_in[6];

    constexpr int B = 8, L1 = 2048, L2 = 2048, H = 1024;
    constexpr size_t NXH   = (size_t)B * L1 * H;
    constexpr size_t NW    = (size_t)H * H;
    constexpr size_t SC_B8 = (size_t)B * L1 * L2 * 4;     // 134 MB
    constexpr size_t SC_B4 = SC_B8 / 2;
    constexpr size_t FIXED = 2 * NW * 2 + 3 * NXH * 2 + B * L2;

    const bool big = ws_size >= SC_B8 + FIXED;
    const size_t sc_bytes = big ? SC_B8 : SC_B4;

    char* ws = (char*)d_ws;
    float*          sc  = (float*)ws;           ws += sc_bytes;
    unsigned short* w1h = (unsigned short*)ws;  ws += NW * 2;
    unsigned short* w2h = (unsigned short*)ws;  ws += NW * 2;
    unsigned short* xp  = (unsigned short*)ws;  ws += NXH * 2;
    unsigned short* yp  = (unsigned short*)ws;  ws += NXH * 2;
    unsigned short* yT  = (unsigned short*)ws;  ws += NXH * 2;
    unsigned char*  mk  = (unsigned char*)ws;   ws += B * L2;
    // xh/yh overlay the score buffer (dead once scores GEMM starts)
    unsigned short* xh = (unsigned short*)sc;
    unsigned short* yh = xh + NXH;

    cvt_f32_f16_kernel<<<(int)(NXH / 4 / 256), 256, 0, stream>>>(
        (const float4*)x, (ushort4*)xh, (int)(NXH / 4));
    cvt_f32_f16_kernel<<<(int)(NW / 4 / 256), 256, 0, stream>>>(
        (const float4*)W1, (ushort4*)w1h, (int)(NW / 4));
    cvt_f32_f16_kernel<<<(int)(NW / 4 / 256), 256, 0, stream>>>(
        (const float4*)W2, (ushort4*)w2h, (int)(NW / 4));
    transpose_cvt_kernel<<<dim3(L2 / 64, H / 64, B), 256, 0, stream>>>(y, yh, yT);
    mask_prep_kernel<<<1, 256, 0, stream>>>(ymask_raw, mk);

    constexpr size_t LDSB = 131072;

    // projections: M=16384, N=1024, K=1024; grid 64x4x2
    proj256_kernel<<<dim3(16384 / 256, 1024 / 256, 2), 512, LDSB, stream>>>(
        xh, yh, w1h, w2h, b1, b2, xp, yp);

    const int CB = big ? B : 4;
    for (int c0 = 0; c0 < B; c0 += CB) {
        unsigned short* al = (unsigned short*)sc;   // fp16 alpha in-place, lda 4096

        // scores = x_proj @ y_proj^T : M=2048, N=2048, K=1024
        gemm256_kernel<float, false, false>
            <<<dim3(L1 / 256, L2 / 256, CB), 512, LDSB, stream>>>(
            xp + (size_t)c0 * L1 * H, H, (long long)L1 * H,
            yp + (size_t)c0 * L2 * H, H, (long long)L2 * H,
            sc, L2, (long long)L1 * L2, nullptr, H);

        masked_softmax_kernel<<<CB * L1, 256, 0, stream>>>(
            sc, mk + (size_t)c0 * L2, al, 2 * L2);

        // out = alpha @ yT^T : M=2048, N=1024, K=2048 (alpha lda 4096)
        gemm256_kernel<float, false, false>
            <<<dim3(L1 / 256, H / 256, CB), 512, LDSB, stream>>>(
            al, 2 * L2, (long long)L1 * 2 * L2,
            yT + (size_t)c0 * H * L2, L2, (long long)H * L2,
            (float*)d_out + (size_t)c0 * L1 * H, H, (long long)L1 * H,
            nullptr, L2);
    }
}